// Round 3
// baseline (1866.044 us; speedup 1.0000x reference)
//
#include <hip/hip_runtime.h>

// ---------------------------------------------------------------------------
// PoseVQVAE fused forward. DUAL-MODE: input storage dtype (f32 vs bf16) is
// sniffed on-device from x; all loads/stores branch wave-uniformly on it.
// Math core: bf16-MFMA with multi-plane bf16 splits.
//   encoder chain (fc1..fc3, mu, VQ dist): activations 3-plane, weights
//   3-plane, cross-terms i+j<=2 -> mu accurate to ~1e-6 (argmin-safe).
//   decoder (fc4..out): 1-plane bf16 (tolerance-bound, threshold ~0.045).
// ---------------------------------------------------------------------------

using short8 = __attribute__((ext_vector_type(8))) short;
using f32x4  = __attribute__((ext_vector_type(4))) float;

#define USHORT unsigned short
#define UINT   unsigned int

// plane sizes in ushorts
#define PS_W1  139264   // 544*256
#define PS_W2  65536    // 256*256
#define PS_MU  16384    // 256*64
#define PS_WE  65536    // 64*1024

// ---- ws layout (bytes), 64B-aligned ----
static const size_t OFF_IDX    = 0;         // 65536*4
static const size_t OFF_COUNTS = 262144;    // 1024*4
static const size_t OFF_LOSS   = 266240;    // 4 (+pad)
static const size_t OFF_ENORM  = 266304;    // 1024*4
static const size_t OFF_W1     = 270400;    // 3 planes * 139264 * 2 = 835584
static const size_t OFF_W2     = 1105984;   // 3*65536*2 = 393216
static const size_t OFF_W3     = 1499200;   // 393216
static const size_t OFF_WMU    = 1892416;   // 3*16384*2 = 98304
static const size_t OFF_WE     = 1990720;   // 3*65536*2 = 393216
static const size_t OFF_W4     = 2383936;   // 352*256*2 = 180224
static const size_t OFF_W5     = 2564160;   // 131072
static const size_t OFF_W6     = 2695232;   // 131072
static const size_t OFF_WO     = 2826304;   // 256*272*2 = 139264 -> end ~2.97MB

__device__ __forceinline__ float b2f(USHORT u){
  return __uint_as_float(((UINT)u) << 16);
}
__device__ __forceinline__ USHORT f2b(float f){            // RNE f32->bf16
  UINT u = __float_as_uint(f);
  u += 0x7fffu + ((u >> 16) & 1u);
  return (USHORT)(u >> 16);
}
__device__ __forceinline__ float loadF(const void* p, long i, int f32m){
  if (f32m) return ((const float*)p)[i];
  return b2f(((const USHORT*)p)[i]);
}
__device__ __forceinline__ void split3(float h, USHORT& a, USHORT& b, USHORT& c){
  a = f2b(h); float r = h - b2f(a);
  b = f2b(r); r -= b2f(b);
  c = f2b(r);
}
__device__ __forceinline__ f32x4 mfma16(short8 a, short8 b, f32x4 c){
  return __builtin_amdgcn_mfma_f32_16x16x32_bf16(a, b, c, 0, 0, 0);
}
// dtype sniff: if storage is bf16, low u16 of each u32 is a bf16 ~N(0,1)
// whose exponent field lands in [117,130] w.p. ~0.999; if f32, low u16 is
// mantissa bits (uniform) -> ~5.5%. Ballot over 64 lanes, threshold 32.
__device__ __forceinline__ int detect_f32(const void* x){
  UINT u = ((const UINT*)x)[threadIdx.x & 63];
  int e = (int)((u >> 7) & 0xFFu);
  unsigned long long m = __ballot(e >= 117 && e <= 130);
  return __popcll(m) < 32;
}

// ---------------------------------------------------------------------------
// prep: repack weights into [K/8][N][8] bf16 planes; enorm; zero accums.
// plane p of element t at dst[p*total + t]; t == ((k>>3)*N + n)*8 + (k&7)
// ---------------------------------------------------------------------------
__device__ __forceinline__ void fillW(USHORT* dst, const void* src,
                                      int Kpad, int N, int Ksrc, int Nsrc,
                                      int srcStride, bool kmajor, int t,
                                      int f32m, int planes)
{
  int total = Kpad * N;
  if (t >= total) return;
  int j = t & 7, rest = t >> 3;
  int n = rest % N, kg = rest / N;
  int k = kg*8 + j;
  float v = 0.f;
  if (k < Ksrc && n < Nsrc)
    v = loadF(src, kmajor ? (long)k*srcStride + n : (long)n*srcStride + k, f32m);
  if (planes == 1){ dst[t] = f2b(v); return; }
  USHORT t0, t1, t2; split3(v, t0, t1, t2);
  dst[t] = t0; dst[total + t] = t1; dst[2*total + t] = t2;
}

__global__ void vq_prep_kernel(
    const void* xx,
    const void* fc1w, const void* fc2w, const void* fc3w,
    const void* muw,  const void* fc4w, const void* fc5w,
    const void* fc6w, const void* outw, const void* embed,
    USHORT* W1p, USHORT* W2p, USHORT* W3p, USHORT* Wmup, USHORT* Wep,
    USHORT* W4p, USHORT* W5p, USHORT* W6p, USHORT* Wop,
    float* enorm, UINT* counts, float* loss_sum)
{
  int f32m = detect_f32(xx);
  int t = blockIdx.x * 256 + threadIdx.x;
  switch (blockIdx.y){
    case 0: fillW(W1p,  fc1w, 544, 256, 534, 256, 534, false, t, f32m, 3); break;
    case 1: fillW(W2p,  fc2w, 256, 256, 256, 256, 256, false, t, f32m, 3); break;
    case 2: fillW(W3p,  fc3w, 256, 256, 256, 256, 256, false, t, f32m, 3); break;
    case 3: fillW(Wmup, muw,  256,  64, 256,  64, 256, false, t, f32m, 3); break;
    case 4: fillW(Wep,  embed, 64, 1024, 64, 1024, 1024, true, t, f32m, 3); break;
    case 5: fillW(W4p,  fc4w, 352, 256, 331, 256, 331, false, t, f32m, 1); break;
    case 6: fillW(W5p,  fc5w, 256, 256, 256, 256, 256, false, t, f32m, 1); break;
    case 7: fillW(W6p,  fc6w, 256, 256, 256, 256, 256, false, t, f32m, 1); break;
    case 8: fillW(Wop,  outw, 256, 272, 256, 267, 256, false, t, f32m, 1); break;
    case 9:
      if (t < 1024){
        double s = 0.0;
        for (int l = 0; l < 64; ++l){
          double e = (double)loadF(embed, (long)l*1024 + t, f32m); s += e*e;
        }
        enorm[t] = (float)s;
      }
      break;
    case 10:
      if (t < 1024) counts[t] = 0u;
      if (t == 1024) *loss_sum = 0.f;
      break;
  }
}

// ---------------------------------------------------------------------------
// encoder: 32 rows/block, 128 threads (2 waves, each owns 16 rows).
// fc1 A-fragments built from global loads (no staging). Activations live in
// LDS as 3 bf16 planes sT0/1/2 [32][264]; all rows wave-private.
// ---------------------------------------------------------------------------
__global__ __launch_bounds__(128) void vq_enc_kernel(
    const void* __restrict__ x,  const void* __restrict__ cc,
    const void* __restrict__ b1, const void* __restrict__ b2,
    const void* __restrict__ b3, const void* __restrict__ bmu,
    const void* __restrict__ embed,
    const USHORT* __restrict__ W1p, const USHORT* __restrict__ W2p,
    const USHORT* __restrict__ W3p, const USHORT* __restrict__ Wmup,
    const USHORT* __restrict__ Wep, const float* __restrict__ enorm,
    int* __restrict__ idxws, UINT* __restrict__ counts,
    float* __restrict__ loss_sum)
{
  __shared__ __align__(16) USHORT sT0[32*264];
  __shared__ __align__(16) USHORT sT1[32*264];
  __shared__ __align__(16) USHORT sT2[32*264];

  const int f32m = detect_f32(x);
  const int tid  = threadIdx.x;
  const int w    = tid >> 6;
  const int lane = tid & 63;
  const int quad = lane >> 4;
  const int l16  = lane & 15;
  const int row  = w*16 + l16;                 // local A-frag row (wave-private)
  const long gbase = (long)blockIdx.x * 32;
  const long gr    = gbase + row;              // global row for this lane's A

  f32x4 acc[16];
  #pragma unroll
  for (int i = 0; i < 16; ++i){ acc[i][0]=0.f; acc[i][1]=0.f; acc[i][2]=0.f; acc[i][3]=0.f; }

  // ---- fc1: K=544 (17 chunks of 32); A from global, 3-plane split
  for (int kc = 0; kc < 17; ++kc){
    short8 A0, A1, A2;
    #pragma unroll
    for (int j = 0; j < 8; ++j){
      int col = kc*32 + quad*8 + j;
      float v = 0.f;
      if (col < 267)      v = loadF(x,  gr*267 + col, f32m);
      else if (col < 534) v = loadF(cc, gr*267 + (col - 267), f32m);
      USHORT t0, t1, t2; split3(v, t0, t1, t2);
      A0[j] = (short)t0; A1[j] = (short)t1; A2[j] = (short)t2;
    }
    const USHORT* w0 = W1p + ((kc*4 + quad)*256 + l16)*8;
    if (!f32m){
      // bf16 storage: x/c exact bf16 -> A1=A2=0; single pass
      #pragma unroll
      for (int cb = 0; cb < 16; ++cb){
        short8 B = *(const short8*)(w0 + cb*128);
        acc[cb] = mfma16(A0, B, acc[cb]);
      }
    } else {
      #pragma unroll
      for (int cb = 0; cb < 16; ++cb){
        short8 B = *(const short8*)(w0 + cb*128);
        acc[cb] = mfma16(A0, B, acc[cb]);
        acc[cb] = mfma16(A1, B, acc[cb]);
        acc[cb] = mfma16(A2, B, acc[cb]);
      }
      const USHORT* w1 = w0 + PS_W1;
      #pragma unroll
      for (int cb = 0; cb < 16; ++cb){
        short8 B = *(const short8*)(w1 + cb*128);
        acc[cb] = mfma16(A0, B, acc[cb]);
        acc[cb] = mfma16(A1, B, acc[cb]);
      }
      const USHORT* w2 = w0 + 2*PS_W1;
      #pragma unroll
      for (int cb = 0; cb < 16; ++cb){
        short8 B = *(const short8*)(w2 + cb*128);
        acc[cb] = mfma16(A0, B, acc[cb]);
      }
    }
  }

  #pragma unroll
  for (int cb = 0; cb < 16; ++cb){
    int col = cb*16 + l16;
    float bias = loadF(b1, col, f32m);
    #pragma unroll
    for (int r = 0; r < 4; ++r){
      int orow = w*16 + quad*4 + r;
      float h = fmaxf(acc[cb][r] + bias, 0.f);
      USHORT t0,t1,t2; split3(h, t0,t1,t2);
      sT0[orow*264 + col] = t0;
      sT1[orow*264 + col] = t1;
      sT2[orow*264 + col] = t2;
    }
  }
  __syncthreads();

  // ---- fc2, fc3: in-place, 3-plane A x 3-plane W (i+j<=2), K=256
  for (int layer = 0; layer < 2; ++layer){
    const USHORT* Wp = layer ? W3p : W2p;
    const void*   bb = layer ? b3  : b2;
    #pragma unroll
    for (int i = 0; i < 16; ++i){ acc[i][0]=0.f; acc[i][1]=0.f; acc[i][2]=0.f; acc[i][3]=0.f; }
    for (int kc = 0; kc < 8; ++kc){
      int koff = kc*32 + quad*8;
      short8 A0 = *(const short8*)&sT0[row*264 + koff];
      short8 A1 = *(const short8*)&sT1[row*264 + koff];
      short8 A2 = *(const short8*)&sT2[row*264 + koff];
      const USHORT* w0 = Wp + ((kc*4 + quad)*256 + l16)*8;
      short8 Bf[16];
      #pragma unroll
      for (int cb = 0; cb < 16; ++cb) Bf[cb] = *(const short8*)(w0 + cb*128);
      #pragma unroll
      for (int cb = 0; cb < 16; ++cb) acc[cb] = mfma16(A0, Bf[cb], acc[cb]);
      #pragma unroll
      for (int cb = 0; cb < 16; ++cb) acc[cb] = mfma16(A1, Bf[cb], acc[cb]);
      #pragma unroll
      for (int cb = 0; cb < 16; ++cb) acc[cb] = mfma16(A2, Bf[cb], acc[cb]);
      if (f32m){
        const USHORT* w1 = w0 + PS_W2;
        #pragma unroll
        for (int cb = 0; cb < 16; ++cb) Bf[cb] = *(const short8*)(w1 + cb*128);
        #pragma unroll
        for (int cb = 0; cb < 16; ++cb) acc[cb] = mfma16(A0, Bf[cb], acc[cb]);
        #pragma unroll
        for (int cb = 0; cb < 16; ++cb) acc[cb] = mfma16(A1, Bf[cb], acc[cb]);
        const USHORT* w2 = w0 + 2*PS_W2;
        #pragma unroll
        for (int cb = 0; cb < 16; ++cb) Bf[cb] = *(const short8*)(w2 + cb*128);
        #pragma unroll
        for (int cb = 0; cb < 16; ++cb) acc[cb] = mfma16(A0, Bf[cb], acc[cb]);
      }
    }
    __syncthreads();
    #pragma unroll
    for (int cb = 0; cb < 16; ++cb){
      int col = cb*16 + l16;
      float bias = loadF(bb, col, f32m);
      #pragma unroll
      for (int r = 0; r < 4; ++r){
        int orow = w*16 + quad*4 + r;
        float h = fmaxf(acc[cb][r] + bias, 0.f);
        USHORT t0,t1,t2; split3(h, t0,t1,t2);
        sT0[orow*264 + col] = t0;
        sT1[orow*264 + col] = t1;
        sT2[orow*264 + col] = t2;
      }
    }
    __syncthreads();
  }

  // ---- mu: N=64, no relu; store splits into sT cols 0..63
  f32x4 accm[4];
  #pragma unroll
  for (int i = 0; i < 4; ++i){ accm[i][0]=0.f; accm[i][1]=0.f; accm[i][2]=0.f; accm[i][3]=0.f; }
  for (int kc = 0; kc < 8; ++kc){
    int koff = kc*32 + quad*8;
    short8 A0 = *(const short8*)&sT0[row*264 + koff];
    short8 A1 = *(const short8*)&sT1[row*264 + koff];
    short8 A2 = *(const short8*)&sT2[row*264 + koff];
    const USHORT* w0 = Wmup + ((kc*4 + quad)*64 + l16)*8;
    short8 Bm[4];
    #pragma unroll
    for (int cb = 0; cb < 4; ++cb) Bm[cb] = *(const short8*)(w0 + cb*128);
    #pragma unroll
    for (int cb = 0; cb < 4; ++cb) accm[cb] = mfma16(A0, Bm[cb], accm[cb]);
    #pragma unroll
    for (int cb = 0; cb < 4; ++cb) accm[cb] = mfma16(A1, Bm[cb], accm[cb]);
    #pragma unroll
    for (int cb = 0; cb < 4; ++cb) accm[cb] = mfma16(A2, Bm[cb], accm[cb]);
    if (f32m){
      const USHORT* w1 = w0 + PS_MU;
      #pragma unroll
      for (int cb = 0; cb < 4; ++cb) Bm[cb] = *(const short8*)(w1 + cb*128);
      #pragma unroll
      for (int cb = 0; cb < 4; ++cb) accm[cb] = mfma16(A0, Bm[cb], accm[cb]);
      #pragma unroll
      for (int cb = 0; cb < 4; ++cb) accm[cb] = mfma16(A1, Bm[cb], accm[cb]);
      const USHORT* w2 = w0 + 2*PS_MU;
      #pragma unroll
      for (int cb = 0; cb < 4; ++cb) Bm[cb] = *(const short8*)(w2 + cb*128);
      #pragma unroll
      for (int cb = 0; cb < 4; ++cb) accm[cb] = mfma16(A0, Bm[cb], accm[cb]);
    }
  }
  __syncthreads();
  #pragma unroll
  for (int cb = 0; cb < 4; ++cb){
    int col = cb*16 + l16;
    float bias = loadF(bmu, col, f32m);
    #pragma unroll
    for (int r = 0; r < 4; ++r){
      int orow = w*16 + quad*4 + r;
      float m = accm[cb][r] + bias;
      USHORT t0,t1,t2; split3(m, t0,t1,t2);
      sT0[orow*264 + col] = t0;
      sT1[orow*264 + col] = t1;
      sT2[orow*264 + col] = t2;
    }
  }
  __syncthreads();

  // ---- VQ: argmin_k ( ||e_k||^2 - 2 mu.e_k ), 1024 codes
  short8 MA0[2], MA1[2], MA2[2];
  #pragma unroll
  for (int kc = 0; kc < 2; ++kc){
    int koff = kc*32 + quad*8;
    MA0[kc] = *(const short8*)&sT0[row*264 + koff];
    MA1[kc] = *(const short8*)&sT1[row*264 + koff];
    MA2[kc] = *(const short8*)&sT2[row*264 + koff];
  }
  float minv[4] = {3.4e38f, 3.4e38f, 3.4e38f, 3.4e38f};
  int   minc[4] = {0,0,0,0};
  for (int it = 0; it < 32; ++it){          // 32 codes per iter
    f32x4 ad0, ad1;
    ad0[0]=0.f; ad0[1]=0.f; ad0[2]=0.f; ad0[3]=0.f;
    ad1[0]=0.f; ad1[1]=0.f; ad1[2]=0.f; ad1[3]=0.f;
    #pragma unroll
    for (int kc = 0; kc < 2; ++kc){
      const USHORT* w0 = Wep + ((kc*4 + quad)*1024 + it*32 + l16)*8;
      short8 B00 = *(const short8*)(w0);
      short8 B01 = *(const short8*)(w0 + 128);
      ad0 = mfma16(MA0[kc], B00, ad0);  ad1 = mfma16(MA0[kc], B01, ad1);
      ad0 = mfma16(MA1[kc], B00, ad0);  ad1 = mfma16(MA1[kc], B01, ad1);
      ad0 = mfma16(MA2[kc], B00, ad0);  ad1 = mfma16(MA2[kc], B01, ad1);
      if (f32m){
        const USHORT* w1 = w0 + PS_WE;
        short8 B10 = *(const short8*)(w1);
        short8 B11 = *(const short8*)(w1 + 128);
        ad0 = mfma16(MA0[kc], B10, ad0);  ad1 = mfma16(MA0[kc], B11, ad1);
        ad0 = mfma16(MA1[kc], B10, ad0);  ad1 = mfma16(MA1[kc], B11, ad1);
        const USHORT* w2 = w0 + 2*PS_WE;
        short8 B20 = *(const short8*)(w2);
        short8 B21 = *(const short8*)(w2 + 128);
        ad0 = mfma16(MA0[kc], B20, ad0);  ad1 = mfma16(MA0[kc], B21, ad1);
      }
    }
    int code0 = it*32 + l16, code1 = code0 + 16;
    float en0 = enorm[code0], en1 = enorm[code1];
    #pragma unroll
    for (int r = 0; r < 4; ++r){
      float d0 = en0 - 2.f*ad0[r];
      if (d0 < minv[r]){ minv[r] = d0; minc[r] = code0; }
      float d1 = en1 - 2.f*ad1[r];
      if (d1 < minv[r]){ minv[r] = d1; minc[r] = code1; }
    }
  }
  // reduce across the 16 lanes of each quad (ties -> lowest index)
  #pragma unroll
  for (int off = 8; off >= 1; off >>= 1){
    #pragma unroll
    for (int r = 0; r < 4; ++r){
      float ov = __shfl_xor(minv[r], off, 64);
      int   oc = __shfl_xor(minc[r], off, 64);
      if (ov < minv[r] || (ov == minv[r] && oc < minc[r])){ minv[r] = ov; minc[r] = oc; }
    }
  }

  // ---- emit idx, loss partial, histogram
  float lossp = 0.f;
  #pragma unroll
  for (int r = 0; r < 4; ++r){
    int orow = w*16 + quad*4 + r;
    long grow = gbase + orow;
    int code = minc[r];
    #pragma unroll
    for (int j = 0; j < 4; ++j){
      int l = l16 + j*16;
      float qv = loadF(embed, (long)l*1024 + code, f32m);
      float muf = b2f(sT0[orow*264 + l]) + b2f(sT1[orow*264 + l]) + b2f(sT2[orow*264 + l]);
      float d = qv - muf;
      lossp += d*d;
    }
    if (l16 == 0){
      idxws[grow] = code;
      atomicAdd(&counts[code], 1u);
    }
  }
  #pragma unroll
  for (int off = 32; off >= 1; off >>= 1) lossp += __shfl_xor(lossp, off, 64);
  if (lane == 0) atomicAdd(loss_sum, lossp);
}

// ---------------------------------------------------------------------------
// decoder: 32 rows/block, 128 threads; 1-plane bf16 MFMA (tolerance-bound).
// ---------------------------------------------------------------------------
__global__ __launch_bounds__(128) void vq_dec_kernel(
    const void* __restrict__ x,
    const int* __restrict__ idxws, const void* __restrict__ cc,
    const void* __restrict__ embed,
    const void* __restrict__ b4,  const void* __restrict__ b5,
    const void* __restrict__ b6,  const void* __restrict__ bo,
    const USHORT* __restrict__ W4p, const USHORT* __restrict__ W5p,
    const USHORT* __restrict__ W6p, const USHORT* __restrict__ Wop,
    void* __restrict__ out)
{
  __shared__ __align__(16) USHORT sA[32*360];   // s2 staging / h5 (stride 360)
  __shared__ __align__(16) USHORT sB[32*264];   // h4 / h6       (stride 264)

  const int f32m = detect_f32(x);
  const int tid  = threadIdx.x;
  const int w    = tid >> 6;
  const int lane = tid & 63;
  const int quad = lane >> 4;
  const int l16  = lane & 15;
  const int row  = w*16 + l16;
  const long gbase = (long)blockIdx.x * 32;

  // stage s2 = [q | c | 0pad], width 360 (331 used); q = embed[:, idx[row]]
  for (int rr = 0; rr < 16; ++rr){
    int lr = w*16 + rr;
    int code = idxws[gbase + lr];
    for (int col = lane; col < 360; col += 64){
      float v = 0.f;
      if (col < 64)       v = loadF(embed, (long)col*1024 + code, f32m);
      else if (col < 331) v = loadF(cc, (gbase + lr)*267 + (col - 64), f32m);
      sA[lr*360 + col] = f2b(v);
    }
  }
  __syncthreads();

  f32x4 acc[16];
  // ---- fc4: K=352 (11 chunks) : sA -> sB
  #pragma unroll
  for (int i = 0; i < 16; ++i){ acc[i][0]=0.f; acc[i][1]=0.f; acc[i][2]=0.f; acc[i][3]=0.f; }
  for (int kc = 0; kc < 11; ++kc){
    short8 A = *(const short8*)&sA[row*360 + kc*32 + quad*8];
    const USHORT* wp = W4p + ((kc*4 + quad)*256 + l16)*8;
    #pragma unroll
    for (int cb = 0; cb < 16; ++cb){
      short8 Bf = *(const short8*)(wp + cb*128);
      acc[cb] = mfma16(A, Bf, acc[cb]);
    }
  }
  __syncthreads();
  #pragma unroll
  for (int cb = 0; cb < 16; ++cb){
    int col = cb*16 + l16;
    float bias = loadF(b4, col, f32m);
    #pragma unroll
    for (int r = 0; r < 4; ++r){
      int orow = w*16 + quad*4 + r;
      sB[orow*264 + col] = f2b(fmaxf(acc[cb][r] + bias, 0.f));
    }
  }
  __syncthreads();

  // ---- fc5: sB -> sA
  #pragma unroll
  for (int i = 0; i < 16; ++i){ acc[i][0]=0.f; acc[i][1]=0.f; acc[i][2]=0.f; acc[i][3]=0.f; }
  for (int kc = 0; kc < 8; ++kc){
    short8 A = *(const short8*)&sB[row*264 + kc*32 + quad*8];
    const USHORT* wp = W5p + ((kc*4 + quad)*256 + l16)*8;
    #pragma unroll
    for (int cb = 0; cb < 16; ++cb){
      short8 Bf = *(const short8*)(wp + cb*128);
      acc[cb] = mfma16(A, Bf, acc[cb]);
    }
  }
  __syncthreads();
  #pragma unroll
  for (int cb = 0; cb < 16; ++cb){
    int col = cb*16 + l16;
    float bias = loadF(b5, col, f32m);
    #pragma unroll
    for (int r = 0; r < 4; ++r){
      int orow = w*16 + quad*4 + r;
      sA[orow*360 + col] = f2b(fmaxf(acc[cb][r] + bias, 0.f));
    }
  }
  __syncthreads();

  // ---- fc6: sA -> sB
  #pragma unroll
  for (int i = 0; i < 16; ++i){ acc[i][0]=0.f; acc[i][1]=0.f; acc[i][2]=0.f; acc[i][3]=0.f; }
  for (int kc = 0; kc < 8; ++kc){
    short8 A = *(const short8*)&sA[row*360 + kc*32 + quad*8];
    const USHORT* wp = W6p + ((kc*4 + quad)*256 + l16)*8;
    #pragma unroll
    for (int cb = 0; cb < 16; ++cb){
      short8 Bf = *(const short8*)(wp + cb*128);
      acc[cb] = mfma16(A, Bf, acc[cb]);
    }
  }
  __syncthreads();
  #pragma unroll
  for (int cb = 0; cb < 16; ++cb){
    int col = cb*16 + l16;
    float bias = loadF(b6, col, f32m);
    #pragma unroll
    for (int r = 0; r < 4; ++r){
      int orow = w*16 + quad*4 + r;
      sB[orow*264 + col] = f2b(fmaxf(acc[cb][r] + bias, 0.f));
    }
  }
  __syncthreads();

  // ---- out: N=272 (267 real) : sB -> global
  f32x4 acco[17];
  #pragma unroll
  for (int i = 0; i < 17; ++i){ acco[i][0]=0.f; acco[i][1]=0.f; acco[i][2]=0.f; acco[i][3]=0.f; }
  for (int kc = 0; kc < 8; ++kc){
    short8 A = *(const short8*)&sB[row*264 + kc*32 + quad*8];
    const USHORT* wp = Wop + ((kc*4 + quad)*272 + l16)*8;
    #pragma unroll
    for (int cb = 0; cb < 17; ++cb){
      short8 Bf = *(const short8*)(wp + cb*128);
      acco[cb] = mfma16(A, Bf, acco[cb]);
    }
  }
  #pragma unroll
  for (int cb = 0; cb < 17; ++cb){
    int col = cb*16 + l16;
    if (col < 267){
      float bias = loadF(bo, col, f32m);
      #pragma unroll
      for (int r = 0; r < 4; ++r){
        int orow = w*16 + quad*4 + r;
        long oi = (gbase + orow)*267 + col;
        float val = acco[cb][r] + bias;
        if (f32m) ((float*)out)[oi] = val;
        else      ((USHORT*)out)[oi] = f2b(val);
      }
    }
  }
}

// ---------------------------------------------------------------------------
// finalize: loss mean + perplexity from histogram
// ---------------------------------------------------------------------------
__global__ void vq_fin_kernel(const void* __restrict__ x,
                              const UINT* __restrict__ counts,
                              const float* __restrict__ loss_sum,
                              void* __restrict__ out)
{
  __shared__ float red[4];
  int f32m = detect_f32(x);
  int tid = threadIdx.x;
  float Hl = 0.f;
  for (int k = tid; k < 1024; k += 256){
    float p = (float)counts[k] * (1.f/65536.f);
    Hl -= p * logf(p + 1e-10f);
  }
  #pragma unroll
  for (int off = 32; off >= 1; off >>= 1) Hl += __shfl_xor(Hl, off, 64);
  if ((tid & 63) == 0) red[tid >> 6] = Hl;
  __syncthreads();
  if (tid == 0){
    float H = red[0] + red[1] + red[2] + red[3];
    float loss = *loss_sum * (1.f/4194304.f);   // /(B*L)
    float ppx  = expf(H);
    size_t base = (size_t)65536*267;
    if (f32m){
      ((float*)out)[base]     = loss;
      ((float*)out)[base + 1] = ppx;
    } else {
      ((USHORT*)out)[base]     = f2b(loss);
      ((USHORT*)out)[base + 1] = f2b(ppx);
    }
  }
}

// ---------------------------------------------------------------------------
extern "C" void kernel_launch(void* const* d_in, const int* in_sizes, int n_in,
                              void* d_out, int out_size, void* d_ws, size_t ws_size,
                              hipStream_t stream)
{
  const void* x    = d_in[0];
  const void* c    = d_in[1];
  const void* fc1w = d_in[2];
  const void* fc1b = d_in[3];
  const void* fc2w = d_in[4];
  const void* fc2b = d_in[5];
  const void* fc3w = d_in[6];
  const void* fc3b = d_in[7];
  const void* muw  = d_in[8];
  const void* mub  = d_in[9];
  const void* fc4w = d_in[10];
  const void* fc4b = d_in[11];
  const void* fc5w = d_in[12];
  const void* fc5b = d_in[13];
  const void* fc6w = d_in[14];
  const void* fc6b = d_in[15];
  const void* outw = d_in[16];
  const void* outb = d_in[17];
  const void* embed= d_in[18];

  char* ws = (char*)d_ws;
  int*    idxws  = (int*)   (ws + OFF_IDX);
  UINT*   counts = (UINT*)  (ws + OFF_COUNTS);
  float*  lsum   = (float*) (ws + OFF_LOSS);
  float*  enorm  = (float*) (ws + OFF_ENORM);
  USHORT* W1p = (USHORT*)(ws + OFF_W1);
  USHORT* W2p = (USHORT*)(ws + OFF_W2);
  USHORT* W3p = (USHORT*)(ws + OFF_W3);
  USHORT* Wmup= (USHORT*)(ws + OFF_WMU);
  USHORT* Wep = (USHORT*)(ws + OFF_WE);
  USHORT* W4p = (USHORT*)(ws + OFF_W4);
  USHORT* W5p = (USHORT*)(ws + OFF_W5);
  USHORT* W6p = (USHORT*)(ws + OFF_W6);
  USHORT* Wop = (USHORT*)(ws + OFF_WO);

  dim3 pgrid(544, 11, 1);
  vq_prep_kernel<<<pgrid, 256, 0, stream>>>(
      x, fc1w, fc2w, fc3w, muw, fc4w, fc5w, fc6w, outw, embed,
      W1p, W2p, W3p, Wmup, Wep, W4p, W5p, W6p, Wop, enorm, counts, lsum);

  vq_enc_kernel<<<2048, 128, 0, stream>>>(
      x, c, fc1b, fc2b, fc3b, mub, embed,
      W1p, W2p, W3p, Wmup, Wep, enorm, idxws, counts, lsum);

  vq_dec_kernel<<<2048, 128, 0, stream>>>(
      x, idxws, c, embed, fc4b, fc5b, fc6b, outb,
      W4p, W5p, W6p, Wop, d_out);

  vq_fin_kernel<<<1, 256, 0, stream>>>(x, counts, lsum, d_out);
}